// Round 4
// baseline (646.486 us; speedup 1.0000x reference)
//
#include <hip/hip_runtime.h>

// AbstractLinear: y = x @ W.T + b  (256x8192x8192, bf16 MFMA)
//                 IBP bounds fused on W staging regs (fp32):
//                 P = W@(l+h), R = |W|@(h-l); low=.5(P-R)+b, high=.5(P+R)+b
// R8: LDS-bytes-per-FLOP redesign. R5 model: 80% LDS-port-bound (96 KB/CU/
//     phase at 85 B/cy ~= 1130 of 1435 cy). R7 failed on acc spills (WRITE
//     +40MB, VGPR capped 128) - avoided here (acc=64 VGPR, bounds(256,1)).
//     Geometry: TM=128 TN=64, 4 waves = 2m x 2kh, wave tile 64x64, full K
//     per block (kh k-halves, in-LDS reduction). A-tile read 1x, B 2x ->
//     18.3 FLOP/LDS-byte vs R5's 10.9. x pre-converted to pre-swizzled
//     LDS-linear bf16 (prep kernel, d_ws) -> A staging = ld+st only.
//     W staging keeps R5's pk/swizzle/lgkm-only-barrier machinery.
//     Grid 256 (bid=mt*128+nt: mt pairs share XCD -> W HBM read-once).
#define M_TOTAL 256
#define N_TOTAL 8192
#define K_TOTAL 8192
#define TM 128
#define TN 64
#define BK 64
#define PH 64           // phases per kh half (K/2/BK)

typedef __attribute__((ext_vector_type(4))) float f32x4;
typedef __attribute__((ext_vector_type(8))) short s16x8;
typedef __attribute__((ext_vector_type(4))) int   i32x4;
typedef unsigned short ushort_t;

// pack two fp32 -> two bf16 (truncation) in one v_perm_b32
__device__ __forceinline__ int pk(float a, float b) {
    return (int)__builtin_amdgcn_perm(__float_as_uint(b), __float_as_uint(a), 0x07060302u);
}

// barrier with LDS-visibility only: does NOT drain vmcnt, so global
// prefetch loads issued before it remain in flight.
__device__ __forceinline__ void barrier_lds() {
    asm volatile("s_waitcnt lgkmcnt(0)\n\ts_barrier" ::: "memory");
}

// ---------------- prep: x fp32 -> bf16, pre-swizzled LDS-linear tiles ----
// tile (mt,kh,p) = 16 KB = 1024 chunks of 16 B. chunk ci=(row*8+slot) holds
// bf16(x[mt*128+row][kh*4096+p*64+((slot^(row&7))*8) .. +8]) so the main
// kernel's linear LDS image yields swizzled frag reads with zero VALU.
__global__ __launch_bounds__(256)
void prep_kernel(const float* __restrict__ x,
                 const float* __restrict__ low,
                 const float* __restrict__ high,
                 ushort_t* __restrict__ xpre,
                 float* __restrict__ lhv,
                 float* __restrict__ hlv) {
    const int bx = blockIdx.x, t = threadIdx.x;
    if (bx < 1024) {
        const int gid = bx * 256 + t;        // chunk id, 262144 total
        const int ci  = gid & 1023;
        const int p   = (gid >> 10) & 63;
        const int khh = (gid >> 16) & 1;
        const int mtt = gid >> 17;
        const int row = ci >> 3;             // 0..127
        const int kc  = (ci & 7) ^ (row & 7);
        const float* src = x + (size_t)(mtt * 128 + row) * K_TOTAL
                             + khh * 4096 + p * 64 + kc * 8;
        f32x4 s0 = *(const f32x4*)(src);
        f32x4 s1 = *(const f32x4*)(src + 4);
        i32x4 bi;
        bi[0] = pk(s0[0], s0[1]); bi[1] = pk(s0[2], s0[3]);
        bi[2] = pk(s1[0], s1[1]); bi[3] = pk(s1[2], s1[3]);
        *(i32x4*)(xpre + (size_t)gid * 8) = bi;
    } else {
        const int i = (bx - 1024) * 256 + t; // 8192 lh/hl entries
        float lo = low[i], hi = high[i];
        lhv[i] = lo + hi;
        hlv[i] = hi - lo;
    }
}

// ---------------- main ----------------
__global__ __launch_bounds__(256, 1)
void abstract_linear_kernel(const ushort_t* __restrict__ xpre,
                            const float* __restrict__ W,
                            const float* __restrict__ lh,
                            const float* __restrict__ hl,
                            const float* __restrict__ bias,
                            float* __restrict__ out) {
    __shared__ __align__(16) ushort_t As[2][2][TM * BK];  // [kh][buf] 64 KB
    __shared__ __align__(16) ushort_t Bs[2][2][TN * BK];  // [kh][buf] 32 KB
    __shared__ float ybuf[TM * TN];                        // 32 KB kh-reduce
    __shared__ float pbuf[2][TN];
    __shared__ float rbuf[2][TN];

    const int t    = threadIdx.x;
    const int bx   = blockIdx.x;
    const int nt   = bx & 127;
    const int mt   = bx >> 7;          // mt pairs: bid, bid+128 -> same XCD
    const int n0   = nt * TN;
    const int wave = t >> 6;
    const int m    = wave & 1;         // m-half of wave tile
    const int kh   = wave >> 1;        // k-half 0/1
    const int lane = t & 63;
    const int l15  = lane & 15;
    const int lq   = lane >> 4;
    const int tt   = t & 127;          // thread id within kh staging group
    const int trow = tt >> 3;          // 0..15  (W staging row group)
    const int tk   = tt & 7;           // 0..7   (W staging k chunk)

    f32x4 acc[4][4];                   // wave tile 64x64: 64 VGPR
#pragma unroll
    for (int i = 0; i < 4; ++i)
#pragma unroll
        for (int j = 0; j < 4; ++j)
            acc[i][j] = (f32x4){0.f, 0.f, 0.f, 0.f};

    // bounds: this block covers rows j = jb..jb+1 (mt-split halves the fma)
    const int jb = mt * 2;
    float P[2] = {0.f, 0.f};
    float R[2] = {0.f, 0.f};

    // staging pointers
    const float*    wgp = W + (size_t)(n0 + trow) * K_TOTAL + kh * 4096 + tk * 8;
    const float*    lhp = lh + kh * 4096 + tk * 8;
    const float*    hlp = hl + kh * 4096 + tk * 8;
    const ushort_t* ap  = xpre + (size_t)(mt * 2 + kh) * PH * (TM * BK) + tt * 8;

    // 2-slot register pipelines
    i32x4 areg[2][8];                  // A: 128 B/thread, already bf16
    f32x4 wreg[2][8];                  // W: 4 rows x 8 fp32
    f32x4 lhreg[2][2], hlreg[2][2];

    auto issueA = [&](int sl, int p) {
        const ushort_t* a_p = ap + (size_t)p * (TM * BK);
#pragma unroll
        for (int jj = 0; jj < 8; ++jj)  // chunk jj*128+tt: coalesced 1KB/instr
            areg[sl][jj] = *(const i32x4*)(a_p + jj * 1024);
    };
    auto issueW = [&](int sl, int p) {
        const float* w_p = wgp + p * BK;
#pragma unroll
        for (int j = 0; j < 4; ++j) {
            wreg[sl][j * 2]     = *(const f32x4*)(w_p + (size_t)j * 16 * K_TOTAL);
            wreg[sl][j * 2 + 1] = *(const f32x4*)(w_p + (size_t)j * 16 * K_TOTAL + 4);
        }
        lhreg[sl][0] = *(const f32x4*)(lhp + p * BK);
        lhreg[sl][1] = *(const f32x4*)(lhp + p * BK + 4);
        hlreg[sl][0] = *(const f32x4*)(hlp + p * BK);
        hlreg[sl][1] = *(const f32x4*)(hlp + p * BK + 4);
    };

    const int cwc = (tk ^ (trow & 7)) * 8;   // W swizzled chunk (row&7==trow&7)

    auto convert_write = [&](int sl, int buf) {
        // A: straight copy, xpre is pre-swizzled; linear conflict-free writes
#pragma unroll
        for (int jj = 0; jj < 8; ++jj)
            *(i32x4*)&As[kh][buf][jj * 1024 + tt * 8] = areg[sl][jj];
        // W: pack fp32->bf16, swizzled write
#pragma unroll
        for (int j = 0; j < 4; ++j) {
            f32x4 u0 = wreg[sl][j * 2], u1 = wreg[sl][j * 2 + 1];
            i32x4 d;
            d[0] = pk(u0[0], u0[1]); d[1] = pk(u0[2], u0[3]);
            d[2] = pk(u1[0], u1[1]); d[3] = pk(u1[2], u1[3]);
            *(i32x4*)&Bs[kh][buf][(j * 16 + trow) * BK + cwc] = d;
        }
        // bounds on this block's row-share
#pragma unroll
        for (int jj = 0; jj < 2; ++jj) {
            f32x4 w0 = wreg[sl][(jb + jj) * 2], w1 = wreg[sl][(jb + jj) * 2 + 1];
            f32x4 lA = lhreg[sl][0], lB = lhreg[sl][1];
            f32x4 hA = hlreg[sl][0], hB = hlreg[sl][1];
#pragma unroll
            for (int e = 0; e < 4; ++e) {
                P[jj] = fmaf(w0[e], lA[e], P[jj]);
                P[jj] = fmaf(w1[e], lB[e], P[jj]);
                R[jj] = fmaf(fabsf(w0[e]), hA[e], R[jj]);
                R[jj] = fmaf(fabsf(w1[e]), hB[e], R[jj]);
            }
        }
    };

    const int sw = l15 & 7;            // frag-row swizzle key
    auto mfma_tile = [&](int buf) {
#pragma unroll
        for (int s = 0; s < 2; ++s) {
            const int pos = ((s * 4 + lq) ^ sw) * 8;
            s16x8 af[4], bf[4];
#pragma unroll
            for (int mi = 0; mi < 4; ++mi)
                af[mi] = *(const s16x8*)&As[kh][buf][(m * 64 + mi * 16 + l15) * BK + pos];
#pragma unroll
            for (int ni = 0; ni < 4; ++ni)
                bf[ni] = *(const s16x8*)&Bs[kh][buf][(ni * 16 + l15) * BK + pos];
#pragma unroll
            for (int mi = 0; mi < 4; ++mi)
#pragma unroll
                for (int ni = 0; ni < 4; ++ni)
                    acc[mi][ni] = __builtin_amdgcn_mfma_f32_16x16x32_bf16(
                        af[mi], bf[ni], acc[mi][ni], 0, 0, 0);
        }
    };

    // ---- prologue ----
    issueA(0, 0); issueW(0, 0);
    issueA(1, 1); issueW(1, 1);
    convert_write(0, 0);
    barrier_lds();

    // ---- main pipeline (phase p: buf=p&1, slot=p&1), unrolled x2 ----
    for (int p = 0; p < PH - 2; p += 2) {
        issueA(0, p + 2); issueW(0, p + 2);
        mfma_tile(0);
        convert_write(1, 1);
        barrier_lds();

        issueA(1, p + 3); issueW(1, p + 3);
        mfma_tile(1);
        convert_write(0, 0);
        barrier_lds();
    }
    // tail: phases PH-2, PH-1
    mfma_tile(0);
    convert_write(1, 1);
    barrier_lds();
    mfma_tile(1);

    // ---- bounds partials: reduce over the 8 tk threads sharing a row ----
#pragma unroll
    for (int jj = 0; jj < 2; ++jj) {
        float p2 = P[jj], r2 = R[jj];
        p2 += __shfl_xor(p2, 1); p2 += __shfl_xor(p2, 2); p2 += __shfl_xor(p2, 4);
        r2 += __shfl_xor(r2, 1); r2 += __shfl_xor(r2, 2); r2 += __shfl_xor(r2, 4);
        if ((lane & 7) == 0) {
            pbuf[kh][(jb + jj) * 16 + trow] = p2;
            rbuf[kh][(jb + jj) * 16 + trow] = r2;
        }
    }

    // ---- y: kh0 waves deposit partials, kh1 waves add + store ----
    if (kh == 0) {
#pragma unroll
        for (int mi = 0; mi < 4; ++mi)
#pragma unroll
            for (int ni = 0; ni < 4; ++ni)
#pragma unroll
                for (int r = 0; r < 4; ++r)
                    ybuf[(m * 64 + mi * 16 + lq * 4 + r) * TN + ni * 16 + l15] =
                        acc[mi][ni][r];
    }
    __syncthreads();

    if (kh == 1) {
        float bv[4];
#pragma unroll
        for (int ni = 0; ni < 4; ++ni) bv[ni] = bias[n0 + ni * 16 + l15];
#pragma unroll
        for (int mi = 0; mi < 4; ++mi)
#pragma unroll
            for (int ni = 0; ni < 4; ++ni)
#pragma unroll
                for (int r = 0; r < 4; ++r) {
                    int lrow = m * 64 + mi * 16 + lq * 4 + r;
                    float v = acc[mi][ni][r] + ybuf[lrow * TN + ni * 16 + l15];
                    out[(size_t)(mt * TM + lrow) * N_TOTAL + n0 + ni * 16 + l15] =
                        v + bv[ni];
                }
    }

    // ---- bounds epilogue: this block's 32 rows (mt-split) ----
    if (t < 32) {
        int row = mt * 32 + t;
        float Ps = pbuf[0][row] + pbuf[1][row];
        float Rs = rbuf[0][row] + rbuf[1][row];
        float bb = bias[n0 + row];
        out[(size_t)M_TOTAL * N_TOTAL + n0 + row]           = 0.5f * (Ps - Rs) + bb;
        out[(size_t)M_TOTAL * N_TOTAL + N_TOTAL + n0 + row] = 0.5f * (Ps + Rs) + bb;
    }
}

extern "C" void kernel_launch(void* const* d_in, const int* in_sizes, int n_in,
                              void* d_out, int out_size, void* d_ws, size_t ws_size,
                              hipStream_t stream) {
    const float* x    = (const float*)d_in[0];
    const float* low  = (const float*)d_in[1];
    const float* high = (const float*)d_in[2];
    const float* W    = (const float*)d_in[3];
    const float* b    = (const float*)d_in[4];
    float* out = (float*)d_out;

    // workspace: xpre 4 MB (pre-swizzled bf16 x tiles) + lh 32 KB + hl 32 KB
    ushort_t* xpre = (ushort_t*)d_ws;
    float* lhv = (float*)((char*)d_ws + (size_t)M_TOTAL * K_TOTAL * 2);
    float* hlv = lhv + K_TOTAL;

    hipLaunchKernelGGL(prep_kernel, dim3(1056), dim3(256), 0, stream,
                       x, low, high, xpre, lhv, hlv);
    hipLaunchKernelGGL(abstract_linear_kernel, dim3(256), dim3(256), 0, stream,
                       xpre, W, lhv, hlv, b, out);
}